// Round 6
// baseline (56.051 us; speedup 1.0000x reference)
//
#include <hip/hip_runtime.h>

#define E 1280
#define H 20
#define L 8192
#define D 64
#define CHUNK 128
#define NCHUNK (L / CHUNK)          // 64
#define NF4_ARR (H * L * D / 4)     // 2,621,440 float4 per cache array
#define NF4_TOT (2 * NF4_ARR)       // 5,242,880
#define COPY_BLOCKS 1024
#define COPY_STRIDE (COPY_BLOCKS * 256)      // 262,144
#define COPY_ITERS (NF4_TOT / COPY_STRIDE)   // 20

typedef float f4 __attribute__((ext_vector_type(4)));

// ---------------------------------------------------------------- K1: QKV GEMVs
__global__ void qkv_kernel(const float* __restrict__ hs,
                           const float* __restrict__ Wq, const float* __restrict__ bq,
                           const float* __restrict__ Wk,
                           const float* __restrict__ Wv, const float* __restrict__ bv,
                           float* __restrict__ qkv) {
    int row_global = blockIdx.x * 4 + (threadIdx.x >> 6);   // 0..3839
    int lane = threadIdx.x & 63;
    int mat = row_global / E;     // 0=q, 1=k, 2=v
    int row = row_global - mat * E;
    const float* W = (mat == 0) ? Wq : (mat == 1) ? Wk : Wv;
    const float4* Wrow = (const float4*)(W + (size_t)row * E);
    const float4* h4 = (const float4*)hs;
    float sum = 0.f;
#pragma unroll
    for (int i = 0; i < 5; ++i) {
        int idx = lane + 64 * i;
        float4 w4 = Wrow[idx];
        float4 x4 = h4[idx];
        sum += w4.x * x4.x + w4.y * x4.y + w4.z * x4.z + w4.w * x4.w;
    }
#pragma unroll
    for (int off = 32; off > 0; off >>= 1) sum += __shfl_down(sum, off, 64);
    if (lane == 0) {
        float val;
        if (mat == 0)      val = (sum + bq[row]) * 0.125f;   // scale = 64^-0.5
        else if (mat == 1) val = sum;                        // k: no bias
        else               val = sum + bv[row];
        qkv[mat * E + row] = val;
    }
}

// ---------------------------------------------------------------- K2: fused stream
// grid = 2304 blocks of 256, interleaved roles per group of 9: 5 attn + 4 copy.
// attn blocks: read-only flash-decode chunk (128 rows) -> per-chunk m/sum/o.
// copy blocks: pure grid-stride copy of k_cache,v_cache -> out caches with the
//              single-row substitution at pos. No barriers, fill-like stream.
__global__ void fused_kernel(const float* __restrict__ kc, const float* __restrict__ vc,
                             const float* __restrict__ qkv, const int* __restrict__ pos_p,
                             float* __restrict__ out_k, float* __restrict__ out_v,
                             float* __restrict__ cmax, float* __restrict__ csum,
                             float* __restrict__ o_part) {
    int pos = pos_p[0];
    int g  = blockIdx.x / 9;
    int rm = blockIdx.x - g * 9;

    if (rm >= 5) {
        // ---------------- copy role ----------------
        int job = g * 4 + (rm - 5);          // 0..1023
        const f4* __restrict__ ksrc = (const f4*)kc;
        const f4* __restrict__ vsrc = (const f4*)vc;
        f4* __restrict__ kdst = (f4*)out_k;
        f4* __restrict__ vdst = (f4*)out_v;
        const f4* __restrict__ kn = (const f4*)(qkv + E);
        const f4* __restrict__ vn = (const f4*)(qkv + 2 * E);
        int t0 = job * 256 + threadIdx.x;
#pragma unroll
        for (int j = 0; j < COPY_ITERS; ++j) {
            int idx = t0 + j * COPY_STRIDE;
            bool isv = idx >= NF4_ARR;
            int f = isv ? idx - NF4_ARR : idx;
            f4 val = (isv ? vsrc : ksrc)[f];
            int l = (f >> 4) & (L - 1);
            if (l == pos) {
                int h = f >> 17;             // L*D/4 = 131072 f4 per head
                val = (isv ? vn : kn)[h * 16 + (f & 15)];
            }
            (isv ? vdst : kdst)[f] = val;
        }
        return;
    }

    // ---------------- attn role ----------------
    int job = g * 5 + rm;                    // 0..1279
    int h = job >> 6;                        // / NCHUNK
    int c = job & (NCHUNK - 1);
    int tid = threadIdx.x;
    int wave = tid >> 6;
    int lane = tid & 63;
    int cc = tid & 15;
    int rg = tid >> 4;                       // 0..15

    __shared__ float s_part[CHUNK][17];
    __shared__ float s_w[CHUNK];
    __shared__ float smax4[4];
    __shared__ float spsum[4];
    __shared__ float sacc[4][D];

    float4 q4  = ((const float4*)qkv)[h * 16 + cc];
    float4 kn4 = ((const float4*)(qkv + E))[h * 16 + cc];
    float4 vn4 = ((const float4*)(qkv + 2 * E))[h * 16 + cc];

    size_t base = ((size_t)h * L + (size_t)c * CHUNK) * D;
    const float* kbase = kc + base;
    const float* vbase = vc + base;
    int l0 = c * CHUNK;

    // phase 1: stream K -> dot partials, V -> registers (read-only)
    float4 vreg[CHUNK / 16];
#pragma unroll
    for (int it = 0; it < CHUNK / 16; ++it) {
        int r = it * 16 + rg;
        int l = l0 + r;
        float4 k4 = ((const float4*)(kbase + r * D))[cc];
        if (l == pos) k4 = kn4;
        s_part[r][cc] = k4.x * q4.x + k4.y * q4.y + k4.z * q4.z + k4.w * q4.w;
        float4 v4 = ((const float4*)(vbase + r * D))[cc];
        if (l == pos) v4 = vn4;
        vreg[it] = v4;
    }
    __syncthreads();

    // phase 2: score reduce + softmax weights
    float s = -INFINITY;
    if (tid < CHUNK) {
        float sum = 0.f;
#pragma unroll
        for (int i = 0; i < 16; ++i) sum += s_part[tid][i];
        s = (l0 + tid <= pos) ? sum : -INFINITY;
    }
    float lm = s;
#pragma unroll
    for (int off = 32; off > 0; off >>= 1)
        lm = fmaxf(lm, __shfl_xor(lm, off, 64));
    if (lane == 0) smax4[wave] = lm;
    __syncthreads();
    float m = fmaxf(fmaxf(smax4[0], smax4[1]), fmaxf(smax4[2], smax4[3]));

    float p = 0.f;
    if (tid < CHUNK) {
        p = (s > -1e30f) ? __expf(s - m) : 0.f;
        s_w[tid] = p;
    }
    float ps = p;
#pragma unroll
    for (int off = 32; off > 0; off >>= 1) ps += __shfl_xor(ps, off, 64);
    if (lane == 0) spsum[wave] = ps;
    __syncthreads();

    // phase 3: weighted accumulate from registers
    float4 acc = {0.f, 0.f, 0.f, 0.f};
#pragma unroll
    for (int it = 0; it < CHUNK / 16; ++it) {
        int r = it * 16 + rg;
        float w = s_w[r];
        acc.x += w * vreg[it].x; acc.y += w * vreg[it].y;
        acc.z += w * vreg[it].z; acc.w += w * vreg[it].w;
    }
    acc.x += __shfl_xor(acc.x, 16, 64); acc.y += __shfl_xor(acc.y, 16, 64);
    acc.z += __shfl_xor(acc.z, 16, 64); acc.w += __shfl_xor(acc.w, 16, 64);
    acc.x += __shfl_xor(acc.x, 32, 64); acc.y += __shfl_xor(acc.y, 32, 64);
    acc.z += __shfl_xor(acc.z, 32, 64); acc.w += __shfl_xor(acc.w, 32, 64);
    if ((lane >> 4) == 0) ((float4*)&sacc[wave][cc * 4])[0] = acc;
    __syncthreads();
    if (tid < D) {
        float o = sacc[0][tid] + sacc[1][tid] + sacc[2][tid] + sacc[3][tid];
        o_part[((size_t)h * NCHUNK + c) * D + tid] = o;
        if (tid == 0) {
            cmax[h * NCHUNK + c] = m;
            csum[h * NCHUNK + c] = spsum[0] + spsum[1] + spsum[2] + spsum[3];
        }
    }
}

// ---------------------------------------------------------------- K3: cross-chunk combine
__global__ void combine_kernel(const float* __restrict__ cmax, const float* __restrict__ csum,
                               const float* __restrict__ o_part, float* __restrict__ attn_out) {
    int h = blockIdx.x;
    int d = threadIdx.x;              // 64 threads
    float m = -INFINITY;
#pragma unroll
    for (int c = 0; c < NCHUNK; ++c) m = fmaxf(m, cmax[h * NCHUNK + c]);
    float denom = 0.f, o = 0.f;
#pragma unroll 4
    for (int c = 0; c < NCHUNK; ++c) {
        float mc = cmax[h * NCHUNK + c];
        float sc = (mc > -1e30f) ? __expf(mc - m) : 0.f;
        denom += csum[h * NCHUNK + c] * sc;
        o += o_part[((size_t)h * NCHUNK + c) * D + d] * sc;
    }
    attn_out[h * D + d] = o / denom;
}

// ---------------------------------------------------------------- K4: output GEMV
__global__ void ogemv_kernel(const float* __restrict__ attn_out, const float* __restrict__ Wo,
                             const float* __restrict__ bo, float* __restrict__ out) {
    int row = blockIdx.x * 4 + (threadIdx.x >> 6);
    int lane = threadIdx.x & 63;
    const float4* Wrow = (const float4*)(Wo + (size_t)row * E);
    const float4* x4 = (const float4*)attn_out;
    float sum = 0.f;
#pragma unroll
    for (int i = 0; i < 5; ++i) {
        int idx = lane + 64 * i;
        float4 w4 = Wrow[idx];
        float4 a4 = x4[idx];
        sum += w4.x * a4.x + w4.y * a4.y + w4.z * a4.z + w4.w * a4.w;
    }
#pragma unroll
    for (int off = 32; off > 0; off >>= 1) sum += __shfl_down(sum, off, 64);
    if (lane == 0) out[row] = sum + bo[row];
}

extern "C" void kernel_launch(void* const* d_in, const int* in_sizes, int n_in,
                              void* d_out, int out_size, void* d_ws, size_t ws_size,
                              hipStream_t stream) {
    const float* hs  = (const float*)d_in[0];
    const int*   pos = (const int*)d_in[1];    // int64 LE: low word ok (0<=pos<8192)
    const float* kc  = (const float*)d_in[2];
    const float* vc  = (const float*)d_in[3];
    const float* Wq  = (const float*)d_in[4];
    const float* bq  = (const float*)d_in[5];
    const float* Wk  = (const float*)d_in[6];
    const float* Wv  = (const float*)d_in[7];
    const float* bv  = (const float*)d_in[8];
    const float* Wo  = (const float*)d_in[9];
    const float* bo  = (const float*)d_in[10];

    float* out   = (float*)d_out;                 // [0 : E)        attention output
    float* out_k = out + E;                       // new_k_cache  (H*L*D)
    float* out_v = out_k + (size_t)H * L * D;     // new_v_cache

    float* ws       = (float*)d_ws;
    float* qkv      = ws;                             // 3*E
    float* cmax     = qkv + 3 * E;                    // H*NCHUNK
    float* csum     = cmax + H * NCHUNK;              // H*NCHUNK
    float* o_part   = csum + H * NCHUNK;              // H*NCHUNK*D
    float* attn_out = o_part + (size_t)H * NCHUNK * D;  // E

    qkv_kernel<<<3 * E / 4, 256, 0, stream>>>(hs, Wq, bq, Wk, Wv, bv, qkv);
    fused_kernel<<<2304, 256, 0, stream>>>(kc, vc, qkv, pos, out_k, out_v,
                                           cmax, csum, o_part);
    combine_kernel<<<H, 64, 0, stream>>>(cmax, csum, o_part, attn_out);
    ogemv_kernel<<<E / 4, 256, 0, stream>>>(attn_out, Wo, bo, out);
}